// Round 1
// baseline (110.825 us; speedup 1.0000x reference)
//
#include <hip/hip_runtime.h>
#include <math.h>

#define NUM_CLASSES 1000
#define NV4 250            // float4 chunks per row (1000 floats)
#define BATCH 16384

// One wave (64 lanes) per row. Row stride = 4000 B (16B-aligned) so float4
// loads are legal. Each lane holds up to 4 float4s in registers -> single
// global pass for max, sum-exp, weighted dot, and weight normalizer.
__global__ __launch_bounds__(256) void row_loss_kernel(
    const float* __restrict__ logits,
    const int* __restrict__ targets,
    float* __restrict__ row_loss) {
  const int wave = threadIdx.x >> 6;   // 0..3
  const int lane = threadIdx.x & 63;
  const int b = blockIdx.x * 4 + wave;

  const float4* row = (const float4*)(logits + (size_t)b * NUM_CLASSES);
  const int c = targets[b];

  float4 v[4];
  float m = -INFINITY;
#pragma unroll
  for (int i = 0; i < 4; ++i) {
    const int j = lane + 64 * i;
    if (j < NV4) {
      v[i] = row[j];
      m = fmaxf(m, fmaxf(fmaxf(v[i].x, v[i].y), fmaxf(v[i].z, v[i].w)));
    } else {
      v[i] = make_float4(0.f, 0.f, 0.f, 0.f);
    }
  }
  // wave-wide max (64 lanes)
#pragma unroll
  for (int o = 32; o > 0; o >>= 1) m = fmaxf(m, __shfl_xor(m, o));

  float se = 0.f;   // sum exp(x - m)
  float ws = 0.f;   // sum_{k != c} x_k / (|k-c|+1)
  float tw = 0.f;   // sum_{k != c} 1 / (|k-c|+1)
  float lc = 0.f;   // x_c (only one lane contributes)
#pragma unroll
  for (int i = 0; i < 4; ++i) {
    const int j = lane + 64 * i;
    if (j < NV4) {
      const float xs[4] = {v[i].x, v[i].y, v[i].z, v[i].w};
      const int k0 = j * 4;
#pragma unroll
      for (int e = 0; e < 4; ++e) {
        const int k = k0 + e;
        const float x = xs[e];
        se += __expf(x - m);
        if (k == c) {
          lc = x;
        } else {
          const float w = 1.0f / (float)(abs(k - c) + 1);
          ws += w * x;
          tw += w;
        }
      }
    }
  }
#pragma unroll
  for (int o = 32; o > 0; o >>= 1) {
    se += __shfl_xor(se, o);
    ws += __shfl_xor(ws, o);
    tw += __shfl_xor(tw, o);
    lc += __shfl_xor(lc, o);
  }

  if (lane == 0) {
    const float lse = m + __logf(se);
    // row of M sums to exactly 1.0 -> loss = lse - dot(M_row, x)
    row_loss[b] = lse - (0.9f * lc + 0.1f * (ws / tw));
  }
}

__global__ __launch_bounds__(256) void final_reduce_kernel(
    const float* __restrict__ row_loss, float* __restrict__ out) {
  float s = 0.f;
  for (int i = threadIdx.x; i < BATCH; i += 256) s += row_loss[i];
#pragma unroll
  for (int o = 32; o > 0; o >>= 1) s += __shfl_xor(s, o);
  __shared__ float sw[4];
  if ((threadIdx.x & 63) == 0) sw[threadIdx.x >> 6] = s;
  __syncthreads();
  if (threadIdx.x == 0) {
    out[0] = (sw[0] + sw[1] + sw[2] + sw[3]) * (1.0f / (float)BATCH);
  }
}

extern "C" void kernel_launch(void* const* d_in, const int* in_sizes, int n_in,
                              void* d_out, int out_size, void* d_ws, size_t ws_size,
                              hipStream_t stream) {
  const float* logits = (const float*)d_in[0];
  const int* targets = (const int*)d_in[1];
  float* out = (float*)d_out;
  float* row_loss = (float*)d_ws;   // BATCH floats = 64 KB scratch

  // 4 rows per 256-thread block (one wave per row)
  row_loss_kernel<<<BATCH / 4, 256, 0, stream>>>(logits, targets, row_loss);
  final_reduce_kernel<<<1, 256, 0, stream>>>(row_loss, out);
}

// Round 2
// 97.516 us; speedup vs baseline: 1.1365x; 1.1365x over previous
//
#include <hip/hip_runtime.h>
#include <math.h>

#define NUM_CLASSES 1000
#define NV4 250            // float4 chunks per row (1000 floats)
#define BATCH 16384

// One wave (64 lanes) per row, 4 rows per 256-thread block. Row stride =
// 4000 B (16B-aligned) so float4 loads are legal. Online-softmax: per-lane
// (max, sum-exp) built during the load pass, then ONE 6-step butterfly merges
// all five row statistics — no separate wave-max phase blocking the exps.
__global__ __launch_bounds__(256) void row_loss_kernel(
    const float* __restrict__ logits,
    const int* __restrict__ targets,
    float* __restrict__ row_loss) {
  const int wave = threadIdx.x >> 6;   // 0..3
  const int lane = threadIdx.x & 63;
  const int b = blockIdx.x * 4 + wave;

  const float4* row = (const float4*)(logits + (size_t)b * NUM_CLASSES);
  const int c = __builtin_amdgcn_readfirstlane(targets[b]);  // wave-uniform -> SGPR

  float4 v[4];
#pragma unroll
  for (int i = 0; i < 4; ++i) {
    const int j = lane + 64 * i;
    if (j < NV4) v[i] = row[j];
    else v[i] = make_float4(-INFINITY, -INFINITY, -INFINITY, -INFINITY);
  }

  // per-lane max (pads are -inf; every lane has >= 12 real elements)
  float m = -INFINITY;
#pragma unroll
  for (int i = 0; i < 4; ++i)
    m = fmaxf(m, fmaxf(fmaxf(v[i].x, v[i].y), fmaxf(v[i].z, v[i].w)));

  float se = 0.f;   // sum exp(x - m)       (per-lane m for now)
  float ws = 0.f;   // sum_{k != c} x_k / (|k-c|+1)
  float tw = 0.f;   // sum_{k != c} 1 / (|k-c|+1)
  float lc = 0.f;   // x_c
#pragma unroll
  for (int i = 0; i < 4; ++i) {
    const float xs[4] = {v[i].x, v[i].y, v[i].z, v[i].w};
    const int k0 = (lane + 64 * i) * 4;
#pragma unroll
    for (int e = 0; e < 4; ++e) {
      const int k = k0 + e;
      const float x = xs[e];
      se += __expf(x - m);                 // pad: exp(-inf) = 0
      if (k < NUM_CLASSES) {
        if (k == c) {
          lc = x;
        } else {
          const float w = __builtin_amdgcn_rcpf((float)(abs(k - c) + 1));
          ws = fmaf(w, x, ws);
          tw += w;
        }
      }
    }
  }

  // single butterfly merging (m, se) online-softmax style + 3 plain sums
#pragma unroll
  for (int o = 32; o > 0; o >>= 1) {
    const float mo  = __shfl_xor(m, o);
    const float seo = __shfl_xor(se, o);
    const float wso = __shfl_xor(ws, o);
    const float two = __shfl_xor(tw, o);
    const float lco = __shfl_xor(lc, o);
    const float nm = fmaxf(m, mo);
    se = se * __expf(m - nm) + seo * __expf(mo - nm);
    m = nm;
    ws += wso;
    tw += two;
    lc += lco;
  }

  if (lane == 0) {
    // smoothing row of M sums to exactly 1.0 -> loss = lse - dot(M_row, x)
    row_loss[b] = m + __logf(se) - (0.9f * lc + 0.1f * (ws / tw));
  }
}

__global__ __launch_bounds__(256) void final_reduce_kernel(
    const float4* __restrict__ row_loss, float* __restrict__ out) {
  float s = 0.f;
  for (int i = threadIdx.x; i < BATCH / 4; i += 256) {
    const float4 t = row_loss[i];
    s += (t.x + t.y) + (t.z + t.w);
  }
#pragma unroll
  for (int o = 32; o > 0; o >>= 1) s += __shfl_xor(s, o);
  __shared__ float sw[4];
  if ((threadIdx.x & 63) == 0) sw[threadIdx.x >> 6] = s;
  __syncthreads();
  if (threadIdx.x == 0) {
    out[0] = (sw[0] + sw[1] + sw[2] + sw[3]) * (1.0f / (float)BATCH);
  }
}

extern "C" void kernel_launch(void* const* d_in, const int* in_sizes, int n_in,
                              void* d_out, int out_size, void* d_ws, size_t ws_size,
                              hipStream_t stream) {
  const float* logits = (const float*)d_in[0];
  const int* targets = (const int*)d_in[1];
  float* out = (float*)d_out;
  float* row_loss = (float*)d_ws;   // BATCH floats = 64 KB scratch

  row_loss_kernel<<<BATCH / 4, 256, 0, stream>>>(logits, targets, row_loss);
  final_reduce_kernel<<<1, 256, 0, stream>>>((const float4*)row_loss, out);
}